// Round 9
// baseline (262.856 us; speedup 1.0000x reference)
//
#include <hip/hip_runtime.h>
#include <math.h>

#define D  32
#define BN 16384
#define PP 16

typedef __bf16 bf16x8 __attribute__((ext_vector_type(8)));
typedef __bf16 bf16x4 __attribute__((ext_vector_type(4)));
typedef float  floatx4 __attribute__((ext_vector_type(4)));

// Weight image (per hop): WIH bf16 128 rows x stride 72 elems; WHH bf16 128 x
// stride 40 elems; bias f32[128] = b_ih+b_hh.
#define WIH_OFF     0
#define WHH_OFF     18432
#define BIAS_OFF    28672
#define IMG_BYTES   29184

#define K1 1.44269504088896341f      // log2(e)
#define K2 2.88539008177792681f      // 2*log2(e)

__device__ __forceinline__ float sigf(float x) {
    float e = __builtin_amdgcn_exp2f(-x * K1);
    return __builtin_amdgcn_rcpf(1.0f + e);
}
__device__ __forceinline__ float logsigf(float x) {
    float ax = fabsf(x);
    float l = log1pf(__expf(-ax));
    return (x >= 0.0f) ? -l : x - l;
}

// 8 floats at tab[row*32 + q*8 .. +8) -> bf16x8 (B-fragment of pair's row)
__device__ __forceinline__ bf16x8 load_frag(const float* __restrict__ tab,
                                            int row, int q) {
    const float4* p = (const float4*)(tab + (size_t)row * D + q * 8);
    float4 a = p[0], b = p[1];
    bf16x8 r = { (__bf16)a.x, (__bf16)a.y, (__bf16)a.z, (__bf16)a.w,
                 (__bf16)b.x, (__bf16)b.y, (__bf16)b.z, (__bf16)b.w };
    return r;
}

// Build both weight images: blocks 0-7 -> img0, 8-15 -> img1.
__global__ __launch_bounds__(256)
void prep_weights(const float* __restrict__ w_ih0, const float* __restrict__ w_hh0,
                  const float* __restrict__ b_ih0, const float* __restrict__ b_hh0,
                  const float* __restrict__ w_ih1, const float* __restrict__ w_hh1,
                  const float* __restrict__ b_ih1, const float* __restrict__ b_hh1,
                  float* __restrict__ img0, float* __restrict__ img1)
{
    const bool second = blockIdx.x >= 8;
    const float* w_ih = second ? w_ih1 : w_ih0;
    const float* w_hh = second ? w_hh1 : w_hh0;
    const float* b_ih = second ? b_ih1 : b_ih0;
    const float* b_hh = second ? b_hh1 : b_hh0;
    char* base = (char*)(second ? img1 : img0);
    const int t0 = (blockIdx.x & 7) * 256 + threadIdx.x;   // 0..2047
    for (int idx = t0; idx < 8192; idx += 2048) {
        int n = idx >> 6, k = idx & 63;
        ((__bf16*)(base + WIH_OFF))[n * 72 + k] = (__bf16)w_ih[idx];
    }
    for (int idx = t0; idx < 4096; idx += 2048) {
        int n = idx >> 5, k = idx & 31;
        ((__bf16*)(base + WHH_OFF))[n * 40 + k] = (__bf16)w_hh[idx];
    }
    if (t0 < 128)
        ((float*)(base + BIAS_OFF))[t0] = b_ih[t0] + b_hh[t0];
}

// One LSTM step, swapped orientation: D[gate][pair] = Wih(A,regs)·x(B,regs)
// [+ Whh(A,regs)·h(B,LDS)]. Lane (q=lane>>4, p=lane&15) ends up holding the
// full i/f/g/o quartets for units {4q+r, 16+4q+r} of pair p.
template<bool FIRST, bool LAST>
__device__ __forceinline__ void lstm_step(
    const bf16x8* __restrict__ Wa0, const bf16x8* __restrict__ Wa1,
    const bf16x8* __restrict__ Wh,  const floatx4* __restrict__ biasv,
    char* __restrict__ Hw, bf16x8 bx0, bf16x8 bx1,
    float* __restrict__ cst, float* __restrict__ hlo, float* __restrict__ hhi,
    int q, int bnl)
{
    bf16x8 bh = {};
    if (!FIRST) bh = *(const bf16x8*)(Hw + bnl * 80 + q * 16);

    floatx4 acc[8];
    #pragma unroll
    for (int mt = 0; mt < 8; ++mt) acc[mt] = biasv[mt];
    #pragma unroll
    for (int mt = 0; mt < 8; ++mt) {
        floatx4 a = acc[mt];
        a = __builtin_amdgcn_mfma_f32_16x16x32_bf16(Wa0[mt], bx0, a, 0, 0, 0);
        a = __builtin_amdgcn_mfma_f32_16x16x32_bf16(Wa1[mt], bx1, a, 0, 0, 0);
        if (!FIRST)
            a = __builtin_amdgcn_mfma_f32_16x16x32_bf16(Wh[mt], bh, a, 0, 0, 0);
        acc[mt] = a;
    }

    // quartet for half hf (unit u = 16*hf + 4q + r): tiles {0,2,4,6}+hf
    #pragma unroll
    for (int hf = 0; hf < 2; ++hf) {
        float* hout = hf ? hhi : hlo;
        #pragma unroll
        for (int r = 0; r < 4; ++r) {
            float gi = acc[0 + hf][r], gf = acc[2 + hf][r],
                  gg = acc[4 + hf][r], go = acc[6 + hf][r];
            float Ai = 1.0f + __builtin_amdgcn_exp2f(-gi * K1);
            float Af = 1.0f + __builtin_amdgcn_exp2f(-gf * K1);
            float G2 = __builtin_amdgcn_exp2f(gg * K2);
            float Gp = G2 + 1.0f, Gm = G2 - 1.0f;
            float cold = FIRST ? 0.0f : cst[hf * 4 + r];
            float num = cold * Ai * Gp + Gm * Af;
            float c = num * __builtin_amdgcn_rcpf(Af * Ai * Gp);
            cst[hf * 4 + r] = c;
            float Ao = 1.0f + __builtin_amdgcn_exp2f(-go * K1);
            float C2 = __builtin_amdgcn_exp2f(c * K2);
            hout[r] = (C2 - 1.0f) * __builtin_amdgcn_rcpf(Ao * (C2 + 1.0f));
        }
    }
    if (!LAST) {
        bf16x4 plo = { (__bf16)hlo[0], (__bf16)hlo[1], (__bf16)hlo[2], (__bf16)hlo[3] };
        bf16x4 phi = { (__bf16)hhi[0], (__bf16)hhi[1], (__bf16)hhi[2], (__bf16)hhi[3] };
        *(bf16x4*)(Hw + bnl * 80 + 8 * q)      = plo;   // units 4q..4q+3
        *(bf16x4*)(Hw + bnl * 80 + 32 + 8 * q) = phi;   // units 16+4q..+3
    }
}

// Grid 8192: hop = blockIdx&1. Block = 4 waves, 1 batch (16 pairs) per wave.
// Weight A-fragments hoisted to VGPRs once per wave; the wave-private h buffer
// OVERLAYS the Wih LDS region, so the compiler cannot rematerialize the
// fragment reads (no-alias unprovable) — forced register retention.
__global__ __launch_bounds__(256, 2)
void hop_mfma(const float* __restrict__ user_table,
              const float* __restrict__ ent_table,
              const float* __restrict__ rel_table,
              const float* __restrict__ img0,
              const float* __restrict__ img1,
              const int*   __restrict__ users,
              const int*   __restrict__ items,
              const int*   __restrict__ lp0,     // (NE,P,3)
              const int*   __restrict__ lp1,     // (NE,P,5)
              float* __restrict__ F0,            // (B,32) sum_p h
              float* __restrict__ F1)
{
    __shared__ __align__(16) char lds[IMG_BYTES];

    const bool second = blockIdx.x & 1;
    const int  idx    = blockIdx.x >> 1;
    const int tid  = threadIdx.x;
    const int lane = tid & 63;
    const int wave = tid >> 6;

    // ---- load weight image into LDS ----------------------------------------
    {
        const float4* g = (const float4*)(second ? img1 : img0);
        float4* l = (float4*)lds;
        #pragma unroll
        for (int i = 0; i < 8; ++i) {
            int k = i * 256 + tid;                 // IMG_BYTES/16 = 1824
            if (k < IMG_BYTES / 16) l[k] = g[k];
        }
    }
    __syncthreads();

    const int bnl = lane & 15;    // pair (B col)
    const int q   = lane >> 4;    // k-group / row-subgroup

    // ---- hoist ALL weights to registers as A-fragments ---------------------
    bf16x8 Wa0[8], Wa1[8], Wh[8];
    floatx4 biasv[8];
    #pragma unroll
    for (int mt = 0; mt < 8; ++mt) {
        const int gr = 16 * mt + bnl;              // A row = gate
        Wa0[mt] = *(const bf16x8*)(lds + WIH_OFF + gr * 144 + q * 16);
        Wa1[mt] = *(const bf16x8*)(lds + WIH_OFF + gr * 144 + 64 + q * 16);
        Wh[mt]  = *(const bf16x8*)(lds + WHH_OFF + gr * 80 + q * 16);
        biasv[mt] = *(const floatx4*)(lds + BIAS_OFF + (16 * mt + 4 * q) * 4);
    }
    __syncthreads();   // all frag reads done before h clobbers the Wih region

    char* Hw = lds + wave * 1280;                  // 16 pairs x 80 B, wave-private

    // ---- x B-fragments: lane loads 8 floats of ITS pair's rows -------------
    const int fb   = idx * 4 + wave;               // batch (wave-uniform)
    const int item = items[fb];
    const int user = users[fb];
    const int L    = second ? 5 : 3;
    const int* __restrict__ il = (second ? lp1 : lp0)
        + ((size_t)item * PP + bnl) * L;

    bf16x8 bx0s0, bx1s0, bx0s1, bx1s1, bx0s2 = {}, bx1s2 = {};
    bx0s0 = load_frag(user_table, user, q);
    bx1s0 = load_frag(ent_table, il[0], q);
    bx0s1 = load_frag(rel_table, il[1], q);
    bx1s1 = load_frag(ent_table, il[2], q);
    if (second) {
        bx0s2 = load_frag(rel_table, il[3], q);
        bx1s2 = load_frag(ent_table, il[4], q);
    }

    float cst[8], hlo[4], hhi[4];
    lstm_step<true, false>(Wa0, Wa1, Wh, biasv, Hw, bx0s0, bx1s0, cst, hlo, hhi, q, bnl);
    if (!second) {
        lstm_step<false, true>(Wa0, Wa1, Wh, biasv, Hw, bx0s1, bx1s1, cst, hlo, hhi, q, bnl);
    } else {
        lstm_step<false, false>(Wa0, Wa1, Wh, biasv, Hw, bx0s1, bx1s1, cst, hlo, hhi, q, bnl);
        lstm_step<false, true >(Wa0, Wa1, Wh, biasv, Hw, bx0s2, bx1s2, cst, hlo, hhi, q, bnl);
    }

    // ---- sum over pairs (lanes sharing q, bnl=0..15), write F --------------
    #pragma unroll
    for (int r = 0; r < 4; ++r) {
        #pragma unroll
        for (int m = 1; m < 16; m <<= 1) {
            hlo[r] += __shfl_xor(hlo[r], m);
            hhi[r] += __shfl_xor(hhi[r], m);
        }
    }
    if (bnl == 0) {
        float* Fout = (second ? F1 : F0) + (size_t)fb * D;
        float4 vlo = { hlo[0], hlo[1], hlo[2], hlo[3] };
        float4 vhi = { hhi[0], hhi[1], hhi[2], hhi[3] };
        *(float4*)(Fout + 4 * q)      = vlo;       // units 4q..4q+3
        *(float4*)(Fout + 16 + 4 * q) = vhi;       // units 16+4q..+3
    }
}

// Per b: emb0=(ent[items]+F0)@W^T+b ; emb1=(emb0+F1)@W^T+b ; score=dot(u,emb1);
// outputs + per-block loss partial. 256 thr = 8 b's x 32 j.
__global__ __launch_bounds__(256)
void chain_score(const float* __restrict__ user_table,
                 const float* __restrict__ ent_table,
                 const float* __restrict__ agg_w,
                 const float* __restrict__ agg_b,
                 const int*   __restrict__ users,
                 const int*   __restrict__ items,
                 const int*   __restrict__ ratings,
                 const float* __restrict__ F0,
                 const float* __restrict__ F1,
                 float* __restrict__ out,
                 float* __restrict__ partials)
{
    __shared__ float s[8][33];
    __shared__ float red[8];
    const int tid = threadIdx.x;
    const int bb  = tid >> 5;
    const int j   = tid & 31;
    const int b   = blockIdx.x * 8 + bb;
    const int it  = items[b];

    s[bb][j] = ent_table[(size_t)it * D + j] + F0[(size_t)b * D + j];
    __syncthreads();
    const float* __restrict__ w = agg_w + (size_t)j * D;
    float e0 = agg_b[j];
    #pragma unroll
    for (int k = 0; k < D; ++k) e0 = fmaf(s[bb][k], w[k], e0);
    __syncthreads();
    s[bb][j] = e0 + F1[(size_t)b * D + j];
    __syncthreads();
    float e1 = agg_b[j];
    #pragma unroll
    for (int k = 0; k < D; ++k) e1 = fmaf(s[bb][k], w[k], e1);

    float prod = user_table[(size_t)users[b] * D + j] * e1;
    #pragma unroll
    for (int m = 1; m < 32; m <<= 1) prod += __shfl_xor(prod, m);
    if (j == 0) {
        out[1 + b]      = sigf(prod);
        out[1 + BN + b] = (float)it;
        float r = (float)ratings[b];
        red[bb] = r * logsigf(prod) + (1.0f - r) * logsigf(-prod);
    }
    __syncthreads();
    if (tid == 0) {
        float t = 0.0f;
        #pragma unroll
        for (int qq = 0; qq < 8; ++qq) t += red[qq];
        partials[blockIdx.x] = t;
    }
}

__global__ __launch_bounds__(256)
void loss_kernel(const float* __restrict__ partials, float* __restrict__ out)
{
    __shared__ float red[4];
    const int t = threadIdx.x;
    float v = 0.0f;
    #pragma unroll
    for (int qq = 0; qq < 8; ++qq) v += partials[qq * 256 + t];
    #pragma unroll
    for (int m = 1; m < 64; m <<= 1) v += __shfl_xor(v, m);
    if ((t & 63) == 0) red[t >> 6] = v;
    __syncthreads();
    if (t == 0) out[0] = -(red[0] + red[1] + red[2] + red[3]) / (float)BN;
}

extern "C" void kernel_launch(void* const* d_in, const int* in_sizes, int n_in,
                              void* d_out, int out_size, void* d_ws, size_t ws_size,
                              hipStream_t stream)
{
    const float* user_table = (const float*)d_in[0];
    const float* ent_table  = (const float*)d_in[1];
    const float* rel_table  = (const float*)d_in[2];
    const float* w_ih0 = (const float*)d_in[3];
    const float* w_hh0 = (const float*)d_in[4];
    const float* b_ih0 = (const float*)d_in[5];
    const float* b_hh0 = (const float*)d_in[6];
    const float* w_ih1 = (const float*)d_in[7];
    const float* w_hh1 = (const float*)d_in[8];
    const float* b_ih1 = (const float*)d_in[9];
    const float* b_hh1 = (const float*)d_in[10];
    const float* agg_w = (const float*)d_in[11];
    const float* agg_b = (const float*)d_in[12];
    const int* users   = (const int*)d_in[13];
    const int* items   = (const int*)d_in[14];
    const int* ratings = (const int*)d_in[15];
    const int* lp0     = (const int*)d_in[16];
    const int* lp1     = (const int*)d_in[17];
    float* out = (float*)d_out;

    float* ws       = (float*)d_ws;
    float* F0       = ws;                            // B*32
    float* F1       = ws + (size_t)BN * D;           // B*32
    float* partials = ws + 2 * (size_t)BN * D;       // 2048
    float* img0     = ws + 2 * (size_t)BN * D + 2048;
    float* img1     = img0 + IMG_BYTES / 4;

    prep_weights<<<16, 256, 0, stream>>>(w_ih0, w_hh0, b_ih0, b_hh0,
                                         w_ih1, w_hh1, b_ih1, b_hh1, img0, img1);
    hop_mfma<<<8192, 256, 0, stream>>>(
        user_table, ent_table, rel_table, img0, img1,
        users, items, lp0, lp1, F0, F1);
    chain_score<<<BN / 8, 256, 0, stream>>>(
        user_table, ent_table, agg_w, agg_b, users, items, ratings,
        F0, F1, out, partials);
    loss_kernel<<<1, 256, 0, stream>>>(partials, out);
}